// Round 1
// baseline (272.544 us; speedup 1.0000x reference)
//
#include <hip/hip_runtime.h>
#include <hip/hip_bf16.h>
#include <math.h>

// Problem: B=64, C=3, H=512, W=512 fp32. Output (B,5):
// [cdr, disc_mean, cup_mean, disc_mean, cup_mean]
// cup = label 1, disc = label 2 of channel-argmax; means over softmax probs.

#define BATCH 64
#define CHAN 3
#define HDIM 512
#define WDIM 512
#define HW (HDIM * WDIM)          // 262144
#define RPB 8                     // rows per block
#define THREADS 256
#define VECS_PER_ROW (WDIM / 4)   // 128 float4 per row
#define NV (RPB * VECS_PER_ROW)   // 1024 float4 per block chunk

// ws layout (per-batch accumulators):
//   int   ymin1[B], ymax1[B], ymin2[B], ymax2[B]
//   float sum1[B],  sum2[B]
struct Accum {
    int ymin1[BATCH];
    int ymax1[BATCH];
    int ymin2[BATCH];
    int ymax2[BATCH];
    float sum1[BATCH];
    float sum2[BATCH];
};

__global__ void cdr_init(Accum* acc) {
    int i = threadIdx.x;
    if (i < BATCH) {
        acc->ymin1[i] = HDIM;   // larger than any row index
        acc->ymax1[i] = -1;
        acc->ymin2[i] = HDIM;
        acc->ymax2[i] = -1;
        acc->sum1[i] = 0.0f;
        acc->sum2[i] = 0.0f;
    }
}

__global__ __launch_bounds__(THREADS) void cdr_main(const float* __restrict__ in,
                                                    Accum* __restrict__ acc) {
    const int blocks_per_batch = HDIM / RPB;          // 64
    const int b = blockIdx.x / blocks_per_batch;
    const int chunk = blockIdx.x % blocks_per_batch;
    const int row0 = chunk * RPB;

    const float4* __restrict__ c0 =
        (const float4*)(in + (size_t)b * CHAN * HW + (size_t)row0 * WDIM);
    const float4* __restrict__ c1 = c0 + (HW / 4);
    const float4* __restrict__ c2 = c1 + (HW / 4);

    __shared__ int s_any1[RPB];
    __shared__ int s_any2[RPB];
    __shared__ float s_red1[THREADS / 64];
    __shared__ float s_red2[THREADS / 64];

    if (threadIdx.x < RPB) {
        s_any1[threadIdx.x] = 0;
        s_any2[threadIdx.x] = 0;
    }
    __syncthreads();

    float acc1 = 0.0f, acc2 = 0.0f;

    for (int v = threadIdx.x; v < NV; v += THREADS) {
        float4 a = c0[v];
        float4 bb = c1[v];
        float4 cc = c2[v];

        int f1 = 0, f2 = 0;

#define DO_PX(V0, V1, V2)                                        \
        {                                                        \
            float best = (V0);                                   \
            int lab = 0;                                         \
            if ((V1) > best) { best = (V1); lab = 1; }           \
            if ((V2) > best) { best = (V2); lab = 2; }           \
            f1 |= (lab == 1);                                    \
            f2 |= (lab == 2);                                    \
            float e0 = __expf((V0) - best);                      \
            float e1 = __expf((V1) - best);                      \
            float e2 = __expf((V2) - best);                      \
            float inv = 1.0f / (e0 + e1 + e2);                   \
            acc1 += e1 * inv;                                    \
            acc2 += e2 * inv;                                    \
        }

        DO_PX(a.x, bb.x, cc.x)
        DO_PX(a.y, bb.y, cc.y)
        DO_PX(a.z, bb.z, cc.z)
        DO_PX(a.w, bb.w, cc.w)
#undef DO_PX

        // Row of this vector; uniform across the wave (64 consecutive v,
        // wave base multiple of 64, 128 vecs/row).
        int row = v / VECS_PER_ROW;
        bool w1 = __any(f1);
        bool w2 = __any(f2);
        if ((threadIdx.x & 63) == 0) {
            if (w1) atomicOr(&s_any1[row], 1);
            if (w2) atomicOr(&s_any2[row], 1);
        }
    }

    // Block reduction of softmax prob sums: wave shuffle then LDS.
    for (int off = 32; off > 0; off >>= 1) {
        acc1 += __shfl_down(acc1, off, 64);
        acc2 += __shfl_down(acc2, off, 64);
    }
    int wave = threadIdx.x >> 6;
    if ((threadIdx.x & 63) == 0) {
        s_red1[wave] = acc1;
        s_red2[wave] = acc2;
    }
    __syncthreads();

    if (threadIdx.x == 0) {
        float t1 = 0.0f, t2 = 0.0f;
        for (int w = 0; w < THREADS / 64; ++w) {
            t1 += s_red1[w];
            t2 += s_red2[w];
        }
        atomicAdd(&acc->sum1[b], t1);
        atomicAdd(&acc->sum2[b], t2);

        // Fold the RPB row flags into block-local min/max, then 1 atomic each.
        int bmin1 = HDIM, bmax1 = -1, bmin2 = HDIM, bmax2 = -1;
        for (int r = 0; r < RPB; ++r) {
            int gr = row0 + r;
            if (s_any1[r]) { if (gr < bmin1) bmin1 = gr; if (gr > bmax1) bmax1 = gr; }
            if (s_any2[r]) { if (gr < bmin2) bmin2 = gr; if (gr > bmax2) bmax2 = gr; }
        }
        if (bmax1 >= 0) {
            atomicMin(&acc->ymin1[b], bmin1);
            atomicMax(&acc->ymax1[b], bmax1);
        }
        if (bmax2 >= 0) {
            atomicMin(&acc->ymin2[b], bmin2);
            atomicMax(&acc->ymax2[b], bmax2);
        }
    }
}

__global__ void cdr_finalize(const Accum* __restrict__ acc, float* __restrict__ out) {
    int b = threadIdx.x;
    if (b < BATCH) {
        float h1 = (acc->ymax1[b] >= 0) ? (float)(acc->ymax1[b] - acc->ymin1[b]) : 0.0f;
        float h2 = (acc->ymax2[b] >= 0) ? (float)(acc->ymax2[b] - acc->ymin2[b]) : 0.0f;
        float cdr = h1 / (h2 + 1e-6f);
        float inv_hw = 1.0f / (float)HW;
        float cup_mean = acc->sum1[b] * inv_hw;   // channel 1
        float disc_mean = acc->sum2[b] * inv_hw;  // channel 2
        out[b * 5 + 0] = cdr;
        out[b * 5 + 1] = disc_mean;
        out[b * 5 + 2] = cup_mean;
        out[b * 5 + 3] = disc_mean;
        out[b * 5 + 4] = cup_mean;
    }
}

extern "C" void kernel_launch(void* const* d_in, const int* in_sizes, int n_in,
                              void* d_out, int out_size, void* d_ws, size_t ws_size,
                              hipStream_t stream) {
    const float* in = (const float*)d_in[0];
    float* out = (float*)d_out;
    Accum* acc = (Accum*)d_ws;

    cdr_init<<<1, 64, 0, stream>>>(acc);
    cdr_main<<<BATCH * (HDIM / RPB), THREADS, 0, stream>>>(in, acc);
    cdr_finalize<<<1, 64, 0, stream>>>(acc, out);
}